// Round 8
// baseline (122.041 us; speedup 1.0000x reference)
//
#include <hip/hip_runtime.h>
#include <math.h>

#define EPSBN 1e-3f

// geometry
#define BB 4
#define TT 4
#define C2 512
#define H2 20
#define W2 20
#define HW2 400
#define RR 4
#define KK 9
#define NS 81
#define NT 3
#define NTS 243
#define HID 4

typedef __attribute__((ext_vector_type(8))) short short8;
typedef __attribute__((ext_vector_type(4))) float floatx4;

static __device__ inline unsigned short f2bf(float f) {
    unsigned int u = __float_as_uint(f);
    unsigned int r = (u + 0x7fffu + ((u >> 16) & 1u)) >> 16;
    return (unsigned short)r;
}

// ---------------------------------------------------------------------------
// K_prep: conv2 weights -> bf16 [O][KP], BN scale folded in; shift[o]=b-m*sc
// ---------------------------------------------------------------------------
__global__ void k_prep(const float* __restrict__ w0, const float* __restrict__ w1,
                       const float* __restrict__ w2,
                       const float* __restrict__ g0, const float* __restrict__ b0,
                       const float* __restrict__ m0, const float* __restrict__ v0,
                       const float* __restrict__ g1, const float* __restrict__ b1,
                       const float* __restrict__ m1, const float* __restrict__ v1,
                       const float* __restrict__ g2, const float* __restrict__ b2,
                       const float* __restrict__ m2, const float* __restrict__ v2,
                       unsigned short* __restrict__ wb0, unsigned short* __restrict__ wb1,
                       unsigned short* __restrict__ wb2, float* __restrict__ shift) {
    int i = blockIdx.x * 256 + threadIdx.x;
    if (i < 128 * 160) {
        int o = i / 160, k = i % 160;
        float sc = g0[o] * rsqrtf(v0[o] + EPSBN);
        wb0[i] = f2bf(k < 132 ? w0[o * 132 + k] * sc : 0.f);
        return;
    }
    i -= 128 * 160;
    if (i < 256 * 288) {
        int o = i / 288, k = i % 288;
        float sc = g1[o] * rsqrtf(v1[o] + EPSBN);
        wb1[i] = f2bf(k < 260 ? w1[o * 260 + k] * sc : 0.f);
        return;
    }
    i -= 256 * 288;
    if (i < 512 * 544) {
        int o = i / 544, k = i % 544;
        float sc = g2[o] * rsqrtf(v2[o] + EPSBN);
        wb2[i] = f2bf(k < 516 ? w2[o * 516 + k] * sc : 0.f);
        return;
    }
    i -= 512 * 544;
    if (i < 896) {
        if (i < 128) {
            float sc = g0[i] * rsqrtf(v0[i] + EPSBN);
            shift[i] = b0[i] - m0[i] * sc;
        } else if (i < 384) {
            int o = i - 128;
            float sc = g1[o] * rsqrtf(v1[o] + EPSBN);
            shift[i] = b1[o] - m1[o] * sc;
        } else {
            int o = i - 384;
            float sc = g2[o] * rsqrtf(v2[o] + EPSBN);
            shift[i] = b2[o] - m2[o] * sc;
        }
    }
}

// ---------------------------------------------------------------------------
// K_pad: zero-padded copy of the LAST frame of features2:
//   pad[b][c][28][32], image row r-4, image col col-4; halo = 0.
// ---------------------------------------------------------------------------
__global__ void k_pad(const float* __restrict__ f2, float* __restrict__ pad) {
    int id = blockIdx.x * 256 + threadIdx.x;           // float4 index
    if (id >= BB * C2 * 28 * 8) return;
    int c4 = id & 7;
    int tmp = id >> 3;
    int r = tmp % 28;
    int tmp2 = tmp / 28;
    int c = tmp2 % C2;
    int b = tmp2 / C2;
    float4 v = {0.f, 0.f, 0.f, 0.f};
    if (r >= 4 && r < 24 && c4 >= 1 && c4 <= 5)
        v = *(const float4*)(f2 + ((size_t)(b * TT + (TT - 1)) * C2 + c) * HW2 +
                             (r - 4) * W2 + (c4 - 1) * 4);
    *(float4*)(pad + (size_t)id * 4) = v;
}

// ---------------------------------------------------------------------------
// K_cost3t: cost volume, 3 past frames folded per thread.
// grid: NSP x 9dy x 4b, 128 thr (100 active = pixel quads).
// Per channel: 3 f4 cur loads (pad, shared across t) + 3 f4 past loads;
// 108 accumulators (3t x 9dx x 4px). Stores: 36 f4 into 12-padded dx runs:
// Spart[p][t*108 + dy*12 + dx], TSPAD=336.
// ---------------------------------------------------------------------------
template <int NSP>
__global__ __launch_bounds__(128) void k_cost3t(const float* __restrict__ f2,
                                                const float* __restrict__ pad,
                                                float* __restrict__ Spart) {
    constexpr int CS = C2 / NSP;
    int bi = blockIdx.x;
    int cs = bi % NSP;
    int rem = bi / NSP;
    int dy = rem % 9;
    int b = rem / 9;
    int q = threadIdx.x;
    if (q >= 100) return;
    int h = q / 5;
    int w0 = (q % 5) * 4;
    int p = h * W2 + w0;

    const float* pr = pad + ((size_t)(b * C2 + cs * CS) * 28 + (h + dy)) * 32 + w0;
    const float* pp0 = f2 + ((size_t)(b * TT + 0) * C2 + cs * CS) * HW2 + p;
    const float* pp1 = pp0 + (size_t)C2 * HW2;
    const float* pp2 = pp1 + (size_t)C2 * HW2;

    float acc[3][36];
#pragma unroll
    for (int t = 0; t < 3; ++t)
#pragma unroll
        for (int i = 0; i < 36; ++i) acc[t][i] = 0.f;

    for (int c = 0; c < CS; ++c) {
        float4 ql = *(const float4*)(pr);
        float4 qm = *(const float4*)(pr + 4);
        float4 qr = *(const float4*)(pr + 8);
        float4 v0 = *(const float4*)(pp0);
        float4 v1 = *(const float4*)(pp1);
        float4 v2 = *(const float4*)(pp2);
        float cv[12] = {ql.x, ql.y, ql.z, ql.w,
                        qm.x, qm.y, qm.z, qm.w,
                        qr.x, qr.y, qr.z, qr.w};
        float pv[3][4] = {{v0.x, v0.y, v0.z, v0.w},
                          {v1.x, v1.y, v1.z, v1.w},
                          {v2.x, v2.y, v2.z, v2.w}};
#pragma unroll
        for (int dx = 0; dx < 9; ++dx) {
#pragma unroll
            for (int px = 0; px < 4; ++px) {
                float d = cv[dx + px];
                acc[0][dx * 4 + px] += fabsf(d - pv[0][px]);
                acc[1][dx * 4 + px] += fabsf(d - pv[1][px]);
                acc[2][dx * 4 + px] += fabsf(d - pv[2][px]);
            }
        }
        pr += 28 * 32;
        pp0 += HW2;
        pp1 += HW2;
        pp2 += HW2;
    }

#pragma unroll
    for (int px = 0; px < 4; ++px) {
        float* dst = Spart + ((size_t)(cs * BB + b) * HW2 + (p + px)) * 336 + dy * 12;
#pragma unroll
        for (int t = 0; t < 3; ++t) {
            float4 u0 = {-acc[t][0 + px], -acc[t][4 + px], -acc[t][8 + px], -acc[t][12 + px]};
            float4 u1 = {-acc[t][16 + px], -acc[t][20 + px], -acc[t][24 + px], -acc[t][28 + px]};
            float4 u2 = {-acc[t][32 + px], 0.f, 0.f, 0.f};
            *(float4*)(dst + t * 108) = u0;
            *(float4*)(dst + t * 108 + 4) = u1;
            *(float4*)(dst + t * 108 + 8) = u2;
        }
    }
}

// ---------------------------------------------------------------------------
// K_cost LDS fallback (R6-validated), templated TS
// ---------------------------------------------------------------------------
template <int NSP, int TS>
__global__ __launch_bounds__(128) void k_cost(const float* __restrict__ f2,
                                              float* __restrict__ Spart) {
    constexpr int CS = C2 / NSP;
    __shared__ float curT[2][28][36];
    int bi = blockIdx.x;
    int cs = bi % NSP;
    int rem = bi / NSP;
    int dy = rem % 9; rem /= 9;
    int t = rem % 3;
    int b = rem / 3;
    int tid = threadIdx.x;
    bool act = (tid < 100);
    int q = act ? tid : 0;
    int h = q / 5;
    int w0 = (q % 5) * 4;
    int p = h * W2 + w0;

    const float* cur = f2 + ((size_t)(b * TT + (TT - 1)) * C2 + cs * CS) * HW2;
    const float* pst = f2 + ((size_t)(b * TT + t) * C2 + cs * CS) * HW2;

    for (int i = tid; i < 2 * 28 * 36; i += 128)
        ((float*)curT)[i] = 0.f;
    __syncthreads();

    float acc[36];
#pragma unroll
    for (int i = 0; i < 36; ++i) acc[i] = 0.f;

    if (act) {
        float4 v = *(const float4*)(cur + p);
        *(float4*)&curT[0][h + 4][w0 + 4] = v;
    }
    __syncthreads();

    for (int c = 0; c < CS; ++c) {
        int buf = c & 1;
        if (act) {
            if (c + 1 < CS) {
                float4 v = *(const float4*)(cur + (size_t)(c + 1) * HW2 + p);
                *(float4*)&curT[buf ^ 1][h + 4][w0 + 4] = v;
            }
            const float* base = &curT[buf][h + dy][w0];
            float4 ql = *(const float4*)(base);
            float4 qm = *(const float4*)(base + 4);
            float4 qr = *(const float4*)(base + 8);
            float4 pv = *(const float4*)(pst + (size_t)c * HW2 + p);
            float cv[12] = {ql.x, ql.y, ql.z, ql.w,
                            qm.x, qm.y, qm.z, qm.w,
                            qr.x, qr.y, qr.z, qr.w};
#pragma unroll
            for (int dx = 0; dx < 9; ++dx) {
                acc[dx * 4 + 0] += fabsf(cv[dx + 0] - pv.x);
                acc[dx * 4 + 1] += fabsf(cv[dx + 1] - pv.y);
                acc[dx * 4 + 2] += fabsf(cv[dx + 2] - pv.z);
                acc[dx * 4 + 3] += fabsf(cv[dx + 3] - pv.w);
            }
        }
        __syncthreads();
    }

    if (act) {
        int tsbase = t * NS + dy * KK;
#pragma unroll
        for (int px = 0; px < 4; ++px) {
            float* dst = Spart + ((size_t)(cs * BB + b) * HW2 + (p + px)) * TS + tsbase;
#pragma unroll
            for (int dx = 0; dx < 9; ++dx) dst[dx] = -acc[dx * 4 + px];
        }
    }
}

// ---------------------------------------------------------------------------
// K_smax_conv1: templated on NSP, TS, and index map (P12: 12-padded dx runs)
// ---------------------------------------------------------------------------
template <int NSP, int TS, bool P12>
__global__ __launch_bounds__(256) void k_smax_conv1(
    const float* __restrict__ Spart, const float* __restrict__ w1,
    const float* __restrict__ g1, const float* __restrict__ b1,
    const float* __restrict__ m1, const float* __restrict__ v1,
    float* __restrict__ psim) {
    __shared__ float sS[NTS];
    __shared__ float sP[NTS];
    int bp = blockIdx.x;
    int tid = threadIdx.x;
    if (tid < NTS) {
        int idx;
        if (P12) {
            int t = tid / 81, r = tid % 81;
            idx = t * 108 + (r / 9) * 12 + (r % 9);
        } else {
            idx = tid;
        }
        float S = 0.f;
#pragma unroll
        for (int k = 0; k < NSP; ++k)
            S += Spart[((size_t)(k * BB * HW2) + bp) * TS + idx];
        sS[tid] = S;
    }
    __syncthreads();
    int wave = tid >> 6, lane = tid & 63;
    if (wave < NT) {
        int base = wave * NS;
        float v0 = sS[base + lane];
        float vo = (lane < NS - 64) ? sS[base + 64 + lane] : -1e30f;
        float m = fmaxf(v0, vo);
#pragma unroll
        for (int off = 32; off; off >>= 1) m = fmaxf(m, __shfl_xor(m, off));
        float e0 = __expf(v0 - m);
        float e1 = (lane < NS - 64) ? __expf(vo - m) : 0.f;
        float s = e0 + e1;
#pragma unroll
        for (int off = 32; off; off >>= 1) s += __shfl_xor(s, off);
        float inv = 1.f / s;
        sP[base + lane] = e0 * inv;
        if (lane < NS - 64) sP[base + 64 + lane] = e1 * inv;
    }
    __syncthreads();
    if (tid < 64) {
        int o = tid >> 4, j = tid & 15;
        float acc = 0.f;
#pragma unroll
        for (int mm = 0; mm < 16; ++mm) {
            int k = j + (mm << 4);
            if (k < NTS) acc += w1[o * NTS + k] * sP[k];
        }
#pragma unroll
        for (int off = 8; off; off >>= 1) acc += __shfl_xor(acc, off);
        if (j == 0) {
            float sc = g1[o] * rsqrtf(v1[o] + EPSBN);
            float y = (acc - m1[o]) * sc + b1[o];
            float sig = 1.f / (1.f + __expf(-y));
            psim[(size_t)bp * HID + o] = y * sig;
        }
    }
}

// ---------------------------------------------------------------------------
// K_resize (validated)
// ---------------------------------------------------------------------------
__global__ void k_resize(const float* __restrict__ psim, float* __restrict__ pre0,
                         float* __restrict__ pre1) {
    int id = blockIdx.x * 256 + threadIdx.x;
    int Hi, Wi, bb2, pp;
    float* dst;
    if (id < BB * 6400) {
        Hi = 80; Wi = 80; bb2 = id / 6400; pp = id % 6400; dst = pre0 + (size_t)id * 4;
    } else {
        id -= BB * 6400;
        if (id >= BB * 1600) return;
        Hi = 40; Wi = 40; bb2 = id / 1600; pp = id % 1600; dst = pre1 + (size_t)id * 4;
    }
    int yi = pp / Wi, xi = pp % Wi;
    float cy = yi * (19.0f / (Hi - 1));
    float cx = xi * (19.0f / (Wi - 1));
    int y0 = (int)cy; if (y0 > 19) y0 = 19;
    int x0 = (int)cx; if (x0 > 19) x0 = 19;
    int y1 = min(y0 + 1, 19);
    int x1 = min(x0 + 1, 19);
    float wy = cy - y0, wx = cx - x0;
    const float4* base = (const float4*)psim + (size_t)bb2 * HW2;
    float4 v00 = base[y0 * 20 + x0];
    float4 v01 = base[y0 * 20 + x1];
    float4 v10 = base[y1 * 20 + x0];
    float4 v11 = base[y1 * 20 + x1];
    float4 r0, r1, o4;
    r0.x = v00.x * (1.f - wy) + v10.x * wy; r0.y = v00.y * (1.f - wy) + v10.y * wy;
    r0.z = v00.z * (1.f - wy) + v10.z * wy; r0.w = v00.w * (1.f - wy) + v10.w * wy;
    r1.x = v01.x * (1.f - wy) + v11.x * wy; r1.y = v01.y * (1.f - wy) + v11.y * wy;
    r1.z = v01.z * (1.f - wy) + v11.z * wy; r1.w = v01.w * (1.f - wy) + v11.w * wy;
    o4.x = r0.x * (1.f - wx) + r1.x * wx; o4.y = r0.y * (1.f - wx) + r1.y * wx;
    o4.z = r0.z * (1.f - wx) + r1.z * wx; o4.w = r0.w * (1.f - wx) + r1.w * wx;
    *(float4*)dst = o4;
}

// ---------------------------------------------------------------------------
// K_gemm (validated): out = SiLU(wb @ x + shift), x fused from f + pre,
// LDS-staged [64px][32ch] bf16 per k-step, 4 waves, wave = 32o x 32p MFMA.
// ---------------------------------------------------------------------------
#define XLS_STRIDE 40  // shorts; 80B rows -> 16B aligned, bank-spread
template <int O, int KP, int K, int HW, int TILES>
__global__ __launch_bounds__(256) void k_gemm(
    const float* __restrict__ f,   // [B][T][O][HW], uses t=T-1
    const float* __restrict__ pre, // [B][HW][4]
    const unsigned short* __restrict__ wb, // [O][KP] bf16
    const float* __restrict__ shift,
    float* __restrict__ out) {     // [B][O][HW]
    constexpr int CI = O;
    constexpr int OB = O / 64;
    __shared__ unsigned short xls[64 * XLS_STRIDE];

    int tid = threadIdx.x;
    int lane = tid & 63, wv = tid >> 6;
    int ob = blockIdx.x % OB;
    int rest = blockIdx.x / OB;
    int b = rest / TILES;
    int p0 = (rest % TILES) * 64;

    int l15 = lane & 15, lhi = lane >> 4;
    int o_w = ob * 64 + (wv & 1) * 32;
    int pw_loc = (wv >> 1) * 32;

    int c_l = tid >> 3;        // 0..31
    int pq = (tid & 7) * 8;    // 0..56
    const float* fbase = f + ((size_t)(b * TT + (TT - 1)) * CI) * HW;
    const float* pbase = pre + (size_t)b * HW * 4;

    const short8* aptr0 = (const short8*)(wb + (size_t)(o_w + l15) * KP + lhi * 8);
    const short8* aptr1 = (const short8*)(wb + (size_t)(o_w + 16 + l15) * KP + lhi * 8);

    floatx4 acc00 = {0.f, 0.f, 0.f, 0.f}, acc01 = acc00, acc10 = acc00, acc11 = acc00;

    for (int c0 = 0; c0 < KP; c0 += 32) {
        __syncthreads();
        {
            int c = c0 + c_l;
            float vals[8];
            if (c < CI) {
                const float* src = fbase + (size_t)c * HW + p0 + pq;
                if (p0 + pq + 7 < HW) {
                    float4 a = ((const float4*)src)[0];
                    float4 bq = ((const float4*)src)[1];
                    vals[0] = a.x; vals[1] = a.y; vals[2] = a.z; vals[3] = a.w;
                    vals[4] = bq.x; vals[5] = bq.y; vals[6] = bq.z; vals[7] = bq.w;
                } else {
#pragma unroll
                    for (int i = 0; i < 8; ++i) {
                        int p = p0 + pq + i;
                        vals[i] = (p < HW) ? src[i] : 0.f;
                    }
                }
            } else if (c < K) {
#pragma unroll
                for (int i = 0; i < 8; ++i) {
                    int p = p0 + pq + i;
                    vals[i] = (p < HW) ? pbase[(size_t)p * 4 + (c - CI)] : 0.f;
                }
            } else {
#pragma unroll
                for (int i = 0; i < 8; ++i) vals[i] = 0.f;
            }
#pragma unroll
            for (int i = 0; i < 8; ++i)
                xls[(pq + i) * XLS_STRIDE + c_l] = f2bf(vals[i]);
        }
        __syncthreads();

        short8 ca0 = aptr0[c0 >> 3];
        short8 ca1 = aptr1[c0 >> 3];
        short8 cb0 = *(const short8*)&xls[(pw_loc + l15) * XLS_STRIDE + lhi * 8];
        short8 cb1 = *(const short8*)&xls[(pw_loc + 16 + l15) * XLS_STRIDE + lhi * 8];
        acc00 = __builtin_amdgcn_mfma_f32_16x16x32_bf16(ca0, cb0, acc00, 0, 0, 0);
        acc01 = __builtin_amdgcn_mfma_f32_16x16x32_bf16(ca0, cb1, acc01, 0, 0, 0);
        acc10 = __builtin_amdgcn_mfma_f32_16x16x32_bf16(ca1, cb0, acc10, 0, 0, 0);
        acc11 = __builtin_amdgcn_mfma_f32_16x16x32_bf16(ca1, cb1, acc11, 0, 0, 0);
    }

#pragma unroll
    for (int osub = 0; osub < 2; ++osub) {
#pragma unroll
        for (int psub = 0; psub < 2; ++psub) {
            floatx4 d = osub ? (psub ? acc11 : acc10) : (psub ? acc01 : acc00);
            int p = p0 + pw_loc + psub * 16 + l15;
            int obase = o_w + osub * 16 + lhi * 4;
            if (p < HW) {
#pragma unroll
                for (int r = 0; r < 4; ++r) {
                    int o = obase + r;
                    float y = d[r] + shift[o];
                    float sig = 1.f / (1.f + __expf(-y));
                    out[((size_t)b * O + o) * HW + p] = y * sig;
                }
            }
        }
    }
}

// ---------------------------------------------------------------------------
extern "C" void kernel_launch(void* const* d_in, const int* in_sizes, int n_in,
                              void* d_out, int out_size, void* d_ws, size_t ws_size,
                              hipStream_t stream) {
    const float* f0 = (const float*)d_in[0];
    const float* f1 = (const float*)d_in[1];
    const float* f2 = (const float*)d_in[2];
    const float* w1 = (const float*)d_in[5];
    const float* g1 = (const float*)d_in[6];
    const float* b1 = (const float*)d_in[7];
    const float* m1 = (const float*)d_in[8];
    const float* v1 = (const float*)d_in[9];
    const float* w2_0 = (const float*)d_in[10];
    const float* g2_0 = (const float*)d_in[11];
    const float* b2_0 = (const float*)d_in[12];
    const float* m2_0 = (const float*)d_in[13];
    const float* v2_0 = (const float*)d_in[14];
    const float* w2_1 = (const float*)d_in[15];
    const float* g2_1 = (const float*)d_in[16];
    const float* b2_1 = (const float*)d_in[17];
    const float* m2_1 = (const float*)d_in[18];
    const float* v2_1 = (const float*)d_in[19];
    const float* w2_2 = (const float*)d_in[20];
    const float* g2_2 = (const float*)d_in[21];
    const float* b2_2 = (const float*)d_in[22];
    const float* m2_2 = (const float*)d_in[23];
    const float* v2_2 = (const float*)d_in[24];

    float* ws = (float*)d_ws;
    const size_t TAIL = 321760;
    const size_t PADSZ = (size_t)BB * C2 * 28 * 32;        // 1,835,008 floats
    const size_t SPNEW = (size_t)16 * BB * HW2 * 336;      // 8,601,600 floats
    const size_t SP8 = (size_t)8 * BB * HW2 * 256;         // 3,276,800 floats
    const size_t need_new = (SPNEW + PADSZ + TAIL) * 4;    // ~43.0 MB
    int mode = (ws_size >= need_new) ? 1 : 0;
    size_t spart_elems = mode ? SPNEW : SP8;
    size_t pad_elems = mode ? PADSZ : 0;

    float* Spart = ws;
    float* pad = ws + spart_elems;
    float* psim = pad + pad_elems;
    float* pre0 = psim + 6400;
    float* pre1 = pre0 + 102400;
    unsigned short* wb0 = (unsigned short*)(pre1 + 25600);
    unsigned short* wb1 = wb0 + 20480;
    unsigned short* wb2 = wb1 + 73728;
    float* shift = (float*)(wb2 + 278528);
    float* out = (float*)d_out;

    k_prep<<<dim3(1460), dim3(256), 0, stream>>>(
        w2_0, w2_1, w2_2,
        g2_0, b2_0, m2_0, v2_0,
        g2_1, b2_1, m2_1, v2_1,
        g2_2, b2_2, m2_2, v2_2,
        wb0, wb1, wb2, shift);
    if (mode == 1) {
        k_pad<<<dim3(1792), dim3(256), 0, stream>>>(f2, pad);
        k_cost3t<16><<<dim3(16 * 36), dim3(128), 0, stream>>>(f2, pad, Spart);
        k_smax_conv1<16, 336, true><<<dim3(1600), dim3(256), 0, stream>>>(
            Spart, w1, g1, b1, m1, v1, psim);
    } else {
        k_cost<8, 256><<<dim3(8 * 108), dim3(128), 0, stream>>>(f2, Spart);
        k_smax_conv1<8, 256, false><<<dim3(1600), dim3(256), 0, stream>>>(
            Spart, w1, g1, b1, m1, v1, psim);
    }
    k_resize<<<dim3(125), dim3(256), 0, stream>>>(psim, pre0, pre1);
    k_gemm<128, 160, 132, 6400, 100><<<dim3(800), dim3(256), 0, stream>>>(
        f0, pre0, wb0, shift, out);
    k_gemm<256, 288, 260, 1600, 25><<<dim3(400), dim3(256), 0, stream>>>(
        f1, pre1, wb1, shift + 128, out + 3276800);
    k_gemm<512, 544, 516, 400, 7><<<dim3(224), dim3(256), 0, stream>>>(
        f2, psim, wb2, shift + 384, out + 3276800 + 1638400);
}

// Round 9
// 98.235 us; speedup vs baseline: 1.2423x; 1.2423x over previous
//
#include <hip/hip_runtime.h>
#include <math.h>

#define EPSBN 1e-3f

// geometry
#define BB 4
#define TT 4
#define C2 512
#define H2 20
#define W2 20
#define HW2 400
#define RR 4
#define KK 9
#define NS 81
#define NT 3
#define NTS 243
#define HID 4

typedef __attribute__((ext_vector_type(8))) short short8;
typedef __attribute__((ext_vector_type(4))) float floatx4;

static __device__ inline unsigned short f2bf(float f) {
    unsigned int u = __float_as_uint(f);
    unsigned int r = (u + 0x7fffu + ((u >> 16) & 1u)) >> 16;
    return (unsigned short)r;
}

// ---------------------------------------------------------------------------
// K_prep: conv2 weights -> bf16 [O][KP], BN scale folded in; shift[o]=b-m*sc
// ---------------------------------------------------------------------------
__global__ void k_prep(const float* __restrict__ w0, const float* __restrict__ w1,
                       const float* __restrict__ w2,
                       const float* __restrict__ g0, const float* __restrict__ b0,
                       const float* __restrict__ m0, const float* __restrict__ v0,
                       const float* __restrict__ g1, const float* __restrict__ b1,
                       const float* __restrict__ m1, const float* __restrict__ v1,
                       const float* __restrict__ g2, const float* __restrict__ b2,
                       const float* __restrict__ m2, const float* __restrict__ v2,
                       unsigned short* __restrict__ wb0, unsigned short* __restrict__ wb1,
                       unsigned short* __restrict__ wb2, float* __restrict__ shift) {
    int i = blockIdx.x * 256 + threadIdx.x;
    if (i < 128 * 160) {
        int o = i / 160, k = i % 160;
        float sc = g0[o] * rsqrtf(v0[o] + EPSBN);
        wb0[i] = f2bf(k < 132 ? w0[o * 132 + k] * sc : 0.f);
        return;
    }
    i -= 128 * 160;
    if (i < 256 * 288) {
        int o = i / 288, k = i % 288;
        float sc = g1[o] * rsqrtf(v1[o] + EPSBN);
        wb1[i] = f2bf(k < 260 ? w1[o * 260 + k] * sc : 0.f);
        return;
    }
    i -= 256 * 288;
    if (i < 512 * 544) {
        int o = i / 544, k = i % 544;
        float sc = g2[o] * rsqrtf(v2[o] + EPSBN);
        wb2[i] = f2bf(k < 516 ? w2[o * 516 + k] * sc : 0.f);
        return;
    }
    i -= 512 * 544;
    if (i < 896) {
        if (i < 128) {
            float sc = g0[i] * rsqrtf(v0[i] + EPSBN);
            shift[i] = b0[i] - m0[i] * sc;
        } else if (i < 384) {
            int o = i - 128;
            float sc = g1[o] * rsqrtf(v1[o] + EPSBN);
            shift[i] = b1[o] - m1[o] * sc;
        } else {
            int o = i - 384;
            float sc = g2[o] * rsqrtf(v2[o] + EPSBN);
            shift[i] = b2[o] - m2[o] * sc;
        }
    }
}

// ---------------------------------------------------------------------------
// K_pad: zero-padded copy of the LAST frame of features2:
//   pad[b][c][28][32], image row r-4, image col col-4; halo = 0.
// ---------------------------------------------------------------------------
__global__ void k_pad(const float* __restrict__ f2, float* __restrict__ pad) {
    int id = blockIdx.x * 256 + threadIdx.x;           // float4 index
    if (id >= BB * C2 * 28 * 8) return;
    int c4 = id & 7;
    int tmp = id >> 3;
    int r = tmp % 28;
    int tmp2 = tmp / 28;
    int c = tmp2 % C2;
    int b = tmp2 / C2;
    float4 v = {0.f, 0.f, 0.f, 0.f};
    if (r >= 4 && r < 24 && c4 >= 1 && c4 <= 5)
        v = *(const float4*)(f2 + ((size_t)(b * TT + (TT - 1)) * C2 + c) * HW2 +
                             (r - 4) * W2 + (c4 - 1) * 4);
    *(float4*)(pad + (size_t)id * 4) = v;
}

// ---------------------------------------------------------------------------
// K_cost_cs: R7 load structure + within-block channel split + f4 stores.
// grid: NSPG x 9dy x 3t x 4b = 1728 blocks, 256 thr (2 halves x 100 active).
// Each half accumulates CS=C2/(2*NSPG) channels; LDS reduce; lower half
// stores 12 f4 per thread to Spart[p][t*108 + dy*12 + dx] (TS=336).
// ---------------------------------------------------------------------------
template <int NSPG>
__global__ __launch_bounds__(256) void k_cost_cs(const float* __restrict__ f2,
                                                 const float* __restrict__ pad,
                                                 float* __restrict__ Spart) {
    constexpr int CS = C2 / (NSPG * 2);   // 16 when NSPG=16
    __shared__ float red[36][100];
    int bi = blockIdx.x;
    int cs = bi % NSPG;
    int rem = bi / NSPG;
    int dy = rem % 9; rem /= 9;
    int t = rem % 3;
    int b = rem / 3;
    int tid = threadIdx.x;
    int half = tid >> 7;
    int q = tid & 127;
    bool act = (q < 100);
    int qq = act ? q : 0;
    int h = qq / 5;
    int w0 = (qq % 5) * 4;
    int p = h * W2 + w0;
    int c0 = cs * (2 * CS) + half * CS;

    const float* pr = pad + ((size_t)(b * C2 + c0) * 28 + (h + dy)) * 32 + w0;
    const float* pp = f2 + ((size_t)(b * TT + t) * C2 + c0) * HW2 + p;

    float acc[36];
#pragma unroll
    for (int i = 0; i < 36; ++i) acc[i] = 0.f;

    if (act) {
#pragma unroll 2
        for (int c = 0; c < CS; ++c) {
            float4 ql = *(const float4*)(pr);
            float4 qm = *(const float4*)(pr + 4);
            float4 qr = *(const float4*)(pr + 8);
            float4 pv = *(const float4*)(pp);
            float cv[12] = {ql.x, ql.y, ql.z, ql.w,
                            qm.x, qm.y, qm.z, qm.w,
                            qr.x, qr.y, qr.z, qr.w};
#pragma unroll
            for (int dx = 0; dx < 9; ++dx) {
                acc[dx * 4 + 0] += fabsf(cv[dx + 0] - pv.x);
                acc[dx * 4 + 1] += fabsf(cv[dx + 1] - pv.y);
                acc[dx * 4 + 2] += fabsf(cv[dx + 2] - pv.z);
                acc[dx * 4 + 3] += fabsf(cv[dx + 3] - pv.w);
            }
            pr += 28 * 32;
            pp += HW2;
        }
    }

    if (half == 1 && act) {
#pragma unroll
        for (int i = 0; i < 36; ++i) red[i][qq] = acc[i];
    }
    __syncthreads();
    if (half == 0 && act) {
#pragma unroll
        for (int i = 0; i < 36; ++i) acc[i] += red[i][qq];
#pragma unroll
        for (int px = 0; px < 4; ++px) {
            float* dst = Spart + ((size_t)(cs * BB + b) * HW2 + (p + px)) * 336 +
                         t * 108 + dy * 12;
            float4 u0 = {-acc[0 + px], -acc[4 + px], -acc[8 + px], -acc[12 + px]};
            float4 u1 = {-acc[16 + px], -acc[20 + px], -acc[24 + px], -acc[28 + px]};
            float4 u2 = {-acc[32 + px], 0.f, 0.f, 0.f};
            *(float4*)(dst) = u0;
            *(float4*)(dst + 4) = u1;
            *(float4*)(dst + 8) = u2;
        }
    }
}

// ---------------------------------------------------------------------------
// K_cost_pad (R7-validated, fallback mode1): TS=256 scalar stores
// ---------------------------------------------------------------------------
template <int NSP>
__global__ __launch_bounds__(128) void k_cost_pad(const float* __restrict__ f2,
                                                  const float* __restrict__ pad,
                                                  float* __restrict__ Spart) {
    constexpr int CS = C2 / NSP;
    int bi = blockIdx.x;
    int cs = bi % NSP;
    int rem = bi / NSP;
    int dy = rem % 9; rem /= 9;
    int t = rem % 3;
    int b = rem / 3;
    int q = threadIdx.x;
    if (q >= 100) return;
    int h = q / 5;
    int w0 = (q % 5) * 4;
    int p = h * W2 + w0;

    const float* pr = pad + ((size_t)(b * C2 + cs * CS) * 28 + (h + dy)) * 32 + w0;
    const float* pp = f2 + ((size_t)(b * TT + t) * C2 + cs * CS) * HW2 + p;

    float acc[36];
#pragma unroll
    for (int i = 0; i < 36; ++i) acc[i] = 0.f;

#pragma unroll 2
    for (int c = 0; c < CS; ++c) {
        float4 ql = *(const float4*)(pr);
        float4 qm = *(const float4*)(pr + 4);
        float4 qr = *(const float4*)(pr + 8);
        float4 pv = *(const float4*)(pp);
        float cv[12] = {ql.x, ql.y, ql.z, ql.w,
                        qm.x, qm.y, qm.z, qm.w,
                        qr.x, qr.y, qr.z, qr.w};
#pragma unroll
        for (int dx = 0; dx < 9; ++dx) {
            acc[dx * 4 + 0] += fabsf(cv[dx + 0] - pv.x);
            acc[dx * 4 + 1] += fabsf(cv[dx + 1] - pv.y);
            acc[dx * 4 + 2] += fabsf(cv[dx + 2] - pv.z);
            acc[dx * 4 + 3] += fabsf(cv[dx + 3] - pv.w);
        }
        pr += 28 * 32;
        pp += HW2;
    }

    int tsbase = t * NS + dy * KK;
#pragma unroll
    for (int px = 0; px < 4; ++px) {
        float* dst = Spart + ((size_t)(cs * BB + b) * HW2 + (p + px)) * 256 + tsbase;
#pragma unroll
        for (int dx = 0; dx < 9; ++dx) dst[dx] = -acc[dx * 4 + px];
    }
}

// ---------------------------------------------------------------------------
// K_cost LDS fallback (R6-validated, mode0)
// ---------------------------------------------------------------------------
template <int NSP, int TS>
__global__ __launch_bounds__(128) void k_cost(const float* __restrict__ f2,
                                              float* __restrict__ Spart) {
    constexpr int CS = C2 / NSP;
    __shared__ float curT[2][28][36];
    int bi = blockIdx.x;
    int cs = bi % NSP;
    int rem = bi / NSP;
    int dy = rem % 9; rem /= 9;
    int t = rem % 3;
    int b = rem / 3;
    int tid = threadIdx.x;
    bool act = (tid < 100);
    int q = act ? tid : 0;
    int h = q / 5;
    int w0 = (q % 5) * 4;
    int p = h * W2 + w0;

    const float* cur = f2 + ((size_t)(b * TT + (TT - 1)) * C2 + cs * CS) * HW2;
    const float* pst = f2 + ((size_t)(b * TT + t) * C2 + cs * CS) * HW2;

    for (int i = tid; i < 2 * 28 * 36; i += 128)
        ((float*)curT)[i] = 0.f;
    __syncthreads();

    float acc[36];
#pragma unroll
    for (int i = 0; i < 36; ++i) acc[i] = 0.f;

    if (act) {
        float4 v = *(const float4*)(cur + p);
        *(float4*)&curT[0][h + 4][w0 + 4] = v;
    }
    __syncthreads();

    for (int c = 0; c < CS; ++c) {
        int buf = c & 1;
        if (act) {
            if (c + 1 < CS) {
                float4 v = *(const float4*)(cur + (size_t)(c + 1) * HW2 + p);
                *(float4*)&curT[buf ^ 1][h + 4][w0 + 4] = v;
            }
            const float* base = &curT[buf][h + dy][w0];
            float4 ql = *(const float4*)(base);
            float4 qm = *(const float4*)(base + 4);
            float4 qr = *(const float4*)(base + 8);
            float4 pv = *(const float4*)(pst + (size_t)c * HW2 + p);
            float cv[12] = {ql.x, ql.y, ql.z, ql.w,
                            qm.x, qm.y, qm.z, qm.w,
                            qr.x, qr.y, qr.z, qr.w};
#pragma unroll
            for (int dx = 0; dx < 9; ++dx) {
                acc[dx * 4 + 0] += fabsf(cv[dx + 0] - pv.x);
                acc[dx * 4 + 1] += fabsf(cv[dx + 1] - pv.y);
                acc[dx * 4 + 2] += fabsf(cv[dx + 2] - pv.z);
                acc[dx * 4 + 3] += fabsf(cv[dx + 3] - pv.w);
            }
        }
        __syncthreads();
    }

    if (act) {
        int tsbase = t * NS + dy * KK;
#pragma unroll
        for (int px = 0; px < 4; ++px) {
            float* dst = Spart + ((size_t)(cs * BB + b) * HW2 + (p + px)) * TS + tsbase;
#pragma unroll
            for (int dx = 0; dx < 9; ++dx) dst[dx] = -acc[dx * 4 + px];
        }
    }
}

// ---------------------------------------------------------------------------
// K_smax_conv1: templated on NSP, TS, and index map (P12: 12-padded dx runs)
// ---------------------------------------------------------------------------
template <int NSP, int TS, bool P12>
__global__ __launch_bounds__(256) void k_smax_conv1(
    const float* __restrict__ Spart, const float* __restrict__ w1,
    const float* __restrict__ g1, const float* __restrict__ b1,
    const float* __restrict__ m1, const float* __restrict__ v1,
    float* __restrict__ psim) {
    __shared__ float sS[NTS];
    __shared__ float sP[NTS];
    int bp = blockIdx.x;
    int tid = threadIdx.x;
    if (tid < NTS) {
        int idx;
        if (P12) {
            int t = tid / 81, r = tid % 81;
            idx = t * 108 + (r / 9) * 12 + (r % 9);
        } else {
            idx = tid;
        }
        float S = 0.f;
#pragma unroll
        for (int k = 0; k < NSP; ++k)
            S += Spart[((size_t)(k * BB * HW2) + bp) * TS + idx];
        sS[tid] = S;
    }
    __syncthreads();
    int wave = tid >> 6, lane = tid & 63;
    if (wave < NT) {
        int base = wave * NS;
        float v0 = sS[base + lane];
        float vo = (lane < NS - 64) ? sS[base + 64 + lane] : -1e30f;
        float m = fmaxf(v0, vo);
#pragma unroll
        for (int off = 32; off; off >>= 1) m = fmaxf(m, __shfl_xor(m, off));
        float e0 = __expf(v0 - m);
        float e1 = (lane < NS - 64) ? __expf(vo - m) : 0.f;
        float s = e0 + e1;
#pragma unroll
        for (int off = 32; off; off >>= 1) s += __shfl_xor(s, off);
        float inv = 1.f / s;
        sP[base + lane] = e0 * inv;
        if (lane < NS - 64) sP[base + 64 + lane] = e1 * inv;
    }
    __syncthreads();
    if (tid < 64) {
        int o = tid >> 4, j = tid & 15;
        float acc = 0.f;
#pragma unroll
        for (int mm = 0; mm < 16; ++mm) {
            int k = j + (mm << 4);
            if (k < NTS) acc += w1[o * NTS + k] * sP[k];
        }
#pragma unroll
        for (int off = 8; off; off >>= 1) acc += __shfl_xor(acc, off);
        if (j == 0) {
            float sc = g1[o] * rsqrtf(v1[o] + EPSBN);
            float y = (acc - m1[o]) * sc + b1[o];
            float sig = 1.f / (1.f + __expf(-y));
            psim[(size_t)bp * HID + o] = y * sig;
        }
    }
}

// ---------------------------------------------------------------------------
// K_resize (validated)
// ---------------------------------------------------------------------------
__global__ void k_resize(const float* __restrict__ psim, float* __restrict__ pre0,
                         float* __restrict__ pre1) {
    int id = blockIdx.x * 256 + threadIdx.x;
    int Hi, Wi, bb2, pp;
    float* dst;
    if (id < BB * 6400) {
        Hi = 80; Wi = 80; bb2 = id / 6400; pp = id % 6400; dst = pre0 + (size_t)id * 4;
    } else {
        id -= BB * 6400;
        if (id >= BB * 1600) return;
        Hi = 40; Wi = 40; bb2 = id / 1600; pp = id % 1600; dst = pre1 + (size_t)id * 4;
    }
    int yi = pp / Wi, xi = pp % Wi;
    float cy = yi * (19.0f / (Hi - 1));
    float cx = xi * (19.0f / (Wi - 1));
    int y0 = (int)cy; if (y0 > 19) y0 = 19;
    int x0 = (int)cx; if (x0 > 19) x0 = 19;
    int y1 = min(y0 + 1, 19);
    int x1 = min(x0 + 1, 19);
    float wy = cy - y0, wx = cx - x0;
    const float4* base = (const float4*)psim + (size_t)bb2 * HW2;
    float4 v00 = base[y0 * 20 + x0];
    float4 v01 = base[y0 * 20 + x1];
    float4 v10 = base[y1 * 20 + x0];
    float4 v11 = base[y1 * 20 + x1];
    float4 r0, r1, o4;
    r0.x = v00.x * (1.f - wy) + v10.x * wy; r0.y = v00.y * (1.f - wy) + v10.y * wy;
    r0.z = v00.z * (1.f - wy) + v10.z * wy; r0.w = v00.w * (1.f - wy) + v10.w * wy;
    r1.x = v01.x * (1.f - wy) + v11.x * wy; r1.y = v01.y * (1.f - wy) + v11.y * wy;
    r1.z = v01.z * (1.f - wy) + v11.z * wy; r1.w = v01.w * (1.f - wy) + v11.w * wy;
    o4.x = r0.x * (1.f - wx) + r1.x * wx; o4.y = r0.y * (1.f - wx) + r1.y * wx;
    o4.z = r0.z * (1.f - wx) + r1.z * wx; o4.w = r0.w * (1.f - wx) + r1.w * wx;
    *(float4*)dst = o4;
}

// ---------------------------------------------------------------------------
// K_gemm (validated): out = SiLU(wb @ x + shift), x fused from f + pre,
// LDS-staged [64px][32ch] bf16 per k-step, 4 waves, wave = 32o x 32p MFMA.
// ---------------------------------------------------------------------------
#define XLS_STRIDE 40  // shorts; 80B rows -> 16B aligned, bank-spread
template <int O, int KP, int K, int HW, int TILES>
__global__ __launch_bounds__(256) void k_gemm(
    const float* __restrict__ f,   // [B][T][O][HW], uses t=T-1
    const float* __restrict__ pre, // [B][HW][4]
    const unsigned short* __restrict__ wb, // [O][KP] bf16
    const float* __restrict__ shift,
    float* __restrict__ out) {     // [B][O][HW]
    constexpr int CI = O;
    constexpr int OB = O / 64;
    __shared__ unsigned short xls[64 * XLS_STRIDE];

    int tid = threadIdx.x;
    int lane = tid & 63, wv = tid >> 6;
    int ob = blockIdx.x % OB;
    int rest = blockIdx.x / OB;
    int b = rest / TILES;
    int p0 = (rest % TILES) * 64;

    int l15 = lane & 15, lhi = lane >> 4;
    int o_w = ob * 64 + (wv & 1) * 32;
    int pw_loc = (wv >> 1) * 32;

    int c_l = tid >> 3;        // 0..31
    int pq = (tid & 7) * 8;    // 0..56
    const float* fbase = f + ((size_t)(b * TT + (TT - 1)) * CI) * HW;
    const float* pbase = pre + (size_t)b * HW * 4;

    const short8* aptr0 = (const short8*)(wb + (size_t)(o_w + l15) * KP + lhi * 8);
    const short8* aptr1 = (const short8*)(wb + (size_t)(o_w + 16 + l15) * KP + lhi * 8);

    floatx4 acc00 = {0.f, 0.f, 0.f, 0.f}, acc01 = acc00, acc10 = acc00, acc11 = acc00;

    for (int c0 = 0; c0 < KP; c0 += 32) {
        __syncthreads();
        {
            int c = c0 + c_l;
            float vals[8];
            if (c < CI) {
                const float* src = fbase + (size_t)c * HW + p0 + pq;
                if (p0 + pq + 7 < HW) {
                    float4 a = ((const float4*)src)[0];
                    float4 bq = ((const float4*)src)[1];
                    vals[0] = a.x; vals[1] = a.y; vals[2] = a.z; vals[3] = a.w;
                    vals[4] = bq.x; vals[5] = bq.y; vals[6] = bq.z; vals[7] = bq.w;
                } else {
#pragma unroll
                    for (int i = 0; i < 8; ++i) {
                        int p = p0 + pq + i;
                        vals[i] = (p < HW) ? src[i] : 0.f;
                    }
                }
            } else if (c < K) {
#pragma unroll
                for (int i = 0; i < 8; ++i) {
                    int p = p0 + pq + i;
                    vals[i] = (p < HW) ? pbase[(size_t)p * 4 + (c - CI)] : 0.f;
                }
            } else {
#pragma unroll
                for (int i = 0; i < 8; ++i) vals[i] = 0.f;
            }
#pragma unroll
            for (int i = 0; i < 8; ++i)
                xls[(pq + i) * XLS_STRIDE + c_l] = f2bf(vals[i]);
        }
        __syncthreads();

        short8 ca0 = aptr0[c0 >> 3];
        short8 ca1 = aptr1[c0 >> 3];
        short8 cb0 = *(const short8*)&xls[(pw_loc + l15) * XLS_STRIDE + lhi * 8];
        short8 cb1 = *(const short8*)&xls[(pw_loc + 16 + l15) * XLS_STRIDE + lhi * 8];
        acc00 = __builtin_amdgcn_mfma_f32_16x16x32_bf16(ca0, cb0, acc00, 0, 0, 0);
        acc01 = __builtin_amdgcn_mfma_f32_16x16x32_bf16(ca0, cb1, acc01, 0, 0, 0);
        acc10 = __builtin_amdgcn_mfma_f32_16x16x32_bf16(ca1, cb0, acc10, 0, 0, 0);
        acc11 = __builtin_amdgcn_mfma_f32_16x16x32_bf16(ca1, cb1, acc11, 0, 0, 0);
    }

#pragma unroll
    for (int osub = 0; osub < 2; ++osub) {
#pragma unroll
        for (int psub = 0; psub < 2; ++psub) {
            floatx4 d = osub ? (psub ? acc11 : acc10) : (psub ? acc01 : acc00);
            int p = p0 + pw_loc + psub * 16 + l15;
            int obase = o_w + osub * 16 + lhi * 4;
            if (p < HW) {
#pragma unroll
                for (int r = 0; r < 4; ++r) {
                    int o = obase + r;
                    float y = d[r] + shift[o];
                    float sig = 1.f / (1.f + __expf(-y));
                    out[((size_t)b * O + o) * HW + p] = y * sig;
                }
            }
        }
    }
}

// ---------------------------------------------------------------------------
extern "C" void kernel_launch(void* const* d_in, const int* in_sizes, int n_in,
                              void* d_out, int out_size, void* d_ws, size_t ws_size,
                              hipStream_t stream) {
    const float* f0 = (const float*)d_in[0];
    const float* f1 = (const float*)d_in[1];
    const float* f2 = (const float*)d_in[2];
    const float* w1 = (const float*)d_in[5];
    const float* g1 = (const float*)d_in[6];
    const float* b1 = (const float*)d_in[7];
    const float* m1 = (const float*)d_in[8];
    const float* v1 = (const float*)d_in[9];
    const float* w2_0 = (const float*)d_in[10];
    const float* g2_0 = (const float*)d_in[11];
    const float* b2_0 = (const float*)d_in[12];
    const float* m2_0 = (const float*)d_in[13];
    const float* v2_0 = (const float*)d_in[14];
    const float* w2_1 = (const float*)d_in[15];
    const float* g2_1 = (const float*)d_in[16];
    const float* b2_1 = (const float*)d_in[17];
    const float* m2_1 = (const float*)d_in[18];
    const float* v2_1 = (const float*)d_in[19];
    const float* w2_2 = (const float*)d_in[20];
    const float* g2_2 = (const float*)d_in[21];
    const float* b2_2 = (const float*)d_in[22];
    const float* m2_2 = (const float*)d_in[23];
    const float* v2_2 = (const float*)d_in[24];

    float* ws = (float*)d_ws;
    const size_t TAIL = 321760;
    const size_t PADSZ = (size_t)BB * C2 * 28 * 32;        // 1,835,008 floats
    const size_t SP336 = (size_t)16 * BB * HW2 * 336;      // 8,601,600 floats
    const size_t SP256 = (size_t)16 * BB * HW2 * 256;      // 6,553,600 floats
    const size_t SP8 = (size_t)8 * BB * HW2 * 256;         // 3,276,800 floats
    const size_t need2 = (SP336 + PADSZ + TAIL) * 4;       // ~43.0 MB
    const size_t need1 = (SP256 + PADSZ + TAIL) * 4;       // ~34.8 MB
    int mode = (ws_size >= need2) ? 2 : (ws_size >= need1) ? 1 : 0;
    size_t spart_elems = (mode == 2) ? SP336 : (mode == 1) ? SP256 : SP8;
    size_t pad_elems = (mode >= 1) ? PADSZ : 0;

    float* Spart = ws;
    float* pad = ws + spart_elems;
    float* psim = pad + pad_elems;
    float* pre0 = psim + 6400;
    float* pre1 = pre0 + 102400;
    unsigned short* wb0 = (unsigned short*)(pre1 + 25600);
    unsigned short* wb1 = wb0 + 20480;
    unsigned short* wb2 = wb1 + 73728;
    float* shift = (float*)(wb2 + 278528);
    float* out = (float*)d_out;

    k_prep<<<dim3(1460), dim3(256), 0, stream>>>(
        w2_0, w2_1, w2_2,
        g2_0, b2_0, m2_0, v2_0,
        g2_1, b2_1, m2_1, v2_1,
        g2_2, b2_2, m2_2, v2_2,
        wb0, wb1, wb2, shift);
    if (mode == 2) {
        k_pad<<<dim3(1792), dim3(256), 0, stream>>>(f2, pad);
        k_cost_cs<16><<<dim3(16 * 108), dim3(256), 0, stream>>>(f2, pad, Spart);
        k_smax_conv1<16, 336, true><<<dim3(1600), dim3(256), 0, stream>>>(
            Spart, w1, g1, b1, m1, v1, psim);
    } else if (mode == 1) {
        k_pad<<<dim3(1792), dim3(256), 0, stream>>>(f2, pad);
        k_cost_pad<16><<<dim3(16 * 108), dim3(128), 0, stream>>>(f2, pad, Spart);
        k_smax_conv1<16, 256, false><<<dim3(1600), dim3(256), 0, stream>>>(
            Spart, w1, g1, b1, m1, v1, psim);
    } else {
        k_cost<8, 256><<<dim3(8 * 108), dim3(128), 0, stream>>>(f2, Spart);
        k_smax_conv1<8, 256, false><<<dim3(1600), dim3(256), 0, stream>>>(
            Spart, w1, g1, b1, m1, v1, psim);
    }
    k_resize<<<dim3(125), dim3(256), 0, stream>>>(psim, pre0, pre1);
    k_gemm<128, 160, 132, 6400, 100><<<dim3(800), dim3(256), 0, stream>>>(
        f0, pre0, wb0, shift, out);
    k_gemm<256, 288, 260, 1600, 25><<<dim3(400), dim3(256), 0, stream>>>(
        f1, pre1, wb1, shift + 128, out + 3276800);
    k_gemm<512, 544, 516, 400, 7><<<dim3(224), dim3(256), 0, stream>>>(
        f2, psim, wb2, shift + 384, out + 3276800 + 1638400);
}